// Round 1
// baseline (424.262 us; speedup 1.0000x reference)
//
#include <hip/hip_runtime.h>
#include <math.h>

// ---------------- LDS layout (float offsets) ----------------
constexpr int PS   = 516;   // padded stride for [8][512] arrays (516%32==4 -> conflict-free k-spread)
constexpr int TPAD = 68;    // padded stride for [8][64] arrays
constexpr int oPyt = 0;                    // [8][PS]  Py transposed
constexpr int oPxt = oPyt + 8*PS;          // [8][PS]  Px transposed
constexpr int oU   = oPxt + 8*PS;          // [512]
constexpr int oB   = oU + 512;             // [4096]   b = normed density
constexpr int oQc  = oB + 4096;            // [64][8]
constexpr int oQcT = oQc + 512;            // [8][TPAD]
constexpr int oGp  = oQcT + 8*TPAD;        // [8][64]  per-wave G partials
constexpr int oG   = oGp + 512;            // [64]     G[k*8+l]
constexpr int oH   = oG + 64;              // [64][8]  H = Qc @ G
constexpr int oTp  = oH + 512;             // [8][8][64] T partials
constexpr int oT   = oTp + 4096;           // [8][TPAD]
constexpr int oMp  = oT + 8*TPAD;          // [8][64]  M partials
constexpr int oM   = oMp + 512;            // [64]     M[k*8+l]
constexpr int oT3  = oM + 64;              // [3][8][TPAD] final T0,T1,T2
constexpr int oM5  = oT3 + 3*8*TPAD;       // [5][64]  M00,M01,M02,M10,M20
constexpr int oCd  = oM5 + 320;            // [64]     grid coords c_i
constexpr int oRed = oCd + 64;             // [4][8]   scalar reduce scratch
constexpr int LDS_FLOATS = oRed + 32;      // = 22272 floats = 89088 B

__global__ __launch_bounds__(512)
void ot_sinkhorn_kernel(const float* __restrict__ nd,
                        const float* __restrict__ ud,
                        const float* __restrict__ pts,
                        float* __restrict__ out)
{
    extern __shared__ float s[];
    const int img  = blockIdx.x;
    const int tid  = threadIdx.x;
    const int lane = tid & 63;
    const int w    = tid >> 6;
    const int kk8  = lane >> 3, ll8 = lane & 7;

    // rs[k] = 1/sqrt(5^k * k!)  for exp(yc/5) = sum_k (y^k/s_k)(c^k/s_k)
    const float rs[8] = {1.0f, 0.44721359549995794f, 0.14142135623730950f,
                         0.036514837167011076f, 0.0081649658092772615f,
                         0.0016329931618554521f, 0.00029814239699997195f,
                         5.0395263067896967e-05f};

    // ---------------- per-thread point & basis ----------------
    const float2 p = ((const float2*)pts)[img*512 + tid];
    const float x = p.x * (1.0f/256.0f) - 1.0f;
    const float y = p.y * (1.0f/256.0f) - 1.0f;
    float px[8], py[8];
    {
        const float ex = expf(-x*x*0.1f);
        const float ey = expf(-y*y*0.1f);
        float xp = 1.0f, yp = 1.0f;
        #pragma unroll
        for (int k = 0; k < 8; ++k) {
            px[k] = ex * xp * rs[k];
            py[k] = ey * yp * rs[k];
            xp *= x; yp *= y;
        }
    }
    #pragma unroll
    for (int k = 0; k < 8; ++k) {
        s[oPyt + k*PS + tid] = py[k];
        s[oPxt + k*PS + tid] = px[k];
    }
    #pragma unroll
    for (int m = 0; m < 8; ++m) {
        const int c = tid + 512*m;
        s[oB + c] = nd[(size_t)img*4096 + c];
    }
    {   // Qc[i][k] = exp(-c^2/10) c^k / s_k , c = (8i+4)/256 - 1
        const int i = tid >> 3, k = tid & 7;
        const float c = (float)(i*8 + 4) * (1.0f/256.0f) - 1.0f;
        float cp = 1.0f;
        for (int kk = 0; kk < k; ++kk) cp *= c;
        const float q = expf(-c*c*0.1f) * cp * rs[k];
        s[oQc  + i*8    + k] = q;
        s[oQcT + k*TPAD + i] = q;
        if (k == 0) s[oCd + i] = c;
    }
    float u = 1.0f/512.0f;
    __syncthreads();

    // ---------------- Sinkhorn: 100 iterations ----------------
    for (int it = 0; it < 100; ++it) {
        // A1: publish u
        s[oU + tid] = u;
        __syncthreads();
        // A2: G[k,l] partials = sum_n u_n Py[n,k] Px[n,l]  (wave w covers n in [64w,64w+64))
        {
            float acc = 0.0f;
            const int base = 64*w;
            #pragma unroll
            for (int c4 = 0; c4 < 16; ++c4) {
                const float4 uu = *(const float4*)&s[oU   + base + 4*c4];
                const float4 pv = *(const float4*)&s[oPyt + kk8*PS + base + 4*c4];
                const float4 qv = *(const float4*)&s[oPxt + ll8*PS + base + 4*c4];
                acc += (uu.x*pv.x)*qv.x + (uu.y*pv.y)*qv.y
                     + (uu.z*pv.z)*qv.z + (uu.w*pv.w)*qv.w;
            }
            s[oGp + w*64 + lane] = acc;
        }
        __syncthreads();
        // A3: reduce G
        if (tid < 64) {
            float g = 0.0f;
            #pragma unroll
            for (int r = 0; r < 8; ++r) g += s[oGp + r*64 + tid];
            s[oG + tid] = g;
        }
        __syncthreads();
        // B: H = Qc @ G   (thread -> (i,l))
        {
            const int i = tid >> 3, l = tid & 7;
            float h = 0.0f;
            #pragma unroll
            for (int k = 0; k < 8; ++k)
                h += s[oQc + i*8 + k] * s[oG + k*8 + l];
            s[oH + i*8 + l] = h;
        }
        __syncthreads();
        // C: v[i,j] = b/(H_i . Qc_j + eps), fold into T[k,j] partials (wave w: rows i=8w..8w+7, lane=j)
        {
            float qj[8];
            #pragma unroll
            for (int k = 0; k < 8; ++k) qj[k] = s[oQcT + k*TPAD + lane];
            float t0[8];
            #pragma unroll
            for (int k = 0; k < 8; ++k) t0[k] = 0.0f;
            #pragma unroll
            for (int m = 0; m < 8; ++m) {
                const int i = w*8 + m;
                const float4 h0 = *(const float4*)&s[oH + i*8];
                const float4 h1 = *(const float4*)&s[oH + i*8 + 4];
                const float uk = h0.x*qj[0]+h0.y*qj[1]+h0.z*qj[2]+h0.w*qj[3]
                               + h1.x*qj[4]+h1.y*qj[5]+h1.z*qj[6]+h1.w*qj[7];
                const float v = s[oB + i*64 + lane] / (uk + 1e-16f);
                const float4 q0 = *(const float4*)&s[oQc + i*8];
                const float4 q1 = *(const float4*)&s[oQc + i*8 + 4];
                t0[0] += q0.x*v; t0[1] += q0.y*v; t0[2] += q0.z*v; t0[3] += q0.w*v;
                t0[4] += q1.x*v; t0[5] += q1.y*v; t0[6] += q1.z*v; t0[7] += q1.w*v;
            }
            #pragma unroll
            for (int k = 0; k < 8; ++k) s[oTp + w*512 + k*64 + lane] = t0[k];
        }
        __syncthreads();
        // C2: reduce T[k,j]  ((k,j)=(w,lane))
        {
            float tt = 0.0f;
            #pragma unroll
            for (int r = 0; r < 8; ++r) tt += s[oTp + r*512 + w*64 + lane];
            s[oT + w*TPAD + lane] = tt;
        }
        __syncthreads();
        // D: M[k,l] partials = sum_j T[k,j] Qc[j,l]  (wave w covers j=8w..8w+7)
        {
            float acc = 0.0f;
            #pragma unroll
            for (int m = 0; m < 8; ++m) {
                const int j = 8*w + m;
                acc += s[oT + kk8*TPAD + j] * s[oQcT + ll8*TPAD + j];
            }
            s[oMp + w*64 + lane] = acc;
        }
        __syncthreads();
        // D2: reduce M
        if (tid < 64) {
            float mm = 0.0f;
            #pragma unroll
            for (int r = 0; r < 8; ++r) mm += s[oMp + r*64 + tid];
            s[oM + tid] = mm;
        }
        __syncthreads();
        // E: Kv_n = py^T M px ; u = a/(Kv+eps)
        {
            float kv = 0.0f;
            #pragma unroll
            for (int k = 0; k < 8; ++k) {
                const float4 m0 = *(const float4*)&s[oM + k*8];
                const float4 m1 = *(const float4*)&s[oM + k*8 + 4];
                const float t = m0.x*px[0]+m0.y*px[1]+m0.z*px[2]+m0.w*px[3]
                              + m1.x*px[4]+m1.y*px[5]+m1.z*px[6]+m1.w*px[7];
                kv += py[k]*t;
            }
            u = (1.0f/512.0f) / (kv + 1e-16f);
        }
        // no barrier needed: next write (U) races with nothing reading U
    }

    // ---------------- final pass ----------------
    // v_100 recomputed from surviving H (= Qc@G(u_99)); u = u_100 (register).
    float ot_p = 0.0f, s1_p = 0.0f, sc_p = 0.0f;
    float t0[8], t1[8], t2[8];
    {
        float qj[8];
        #pragma unroll
        for (int k = 0; k < 8; ++k) qj[k] = s[oQcT + k*TPAD + lane];
        #pragma unroll
        for (int k = 0; k < 8; ++k) { t0[k]=0.0f; t1[k]=0.0f; t2[k]=0.0f; }
        #pragma unroll
        for (int m = 0; m < 8; ++m) {
            const int i = w*8 + m;
            const float ci = s[oCd + i];
            const float4 h0 = *(const float4*)&s[oH + i*8];
            const float4 h1 = *(const float4*)&s[oH + i*8 + 4];
            const float uk = h0.x*qj[0]+h0.y*qj[1]+h0.z*qj[2]+h0.w*qj[3]
                           + h1.x*qj[4]+h1.y*qj[5]+h1.z*qj[6]+h1.w*qj[7];
            const float b  = s[oB + i*64 + lane];
            const float v  = b / (uk + 1e-16f);
            const float beta = 10.0f * logf(v + 1e-16f);
            const float sd = ud[(size_t)img*4096 + i*64 + lane];
            ot_p += b*beta;
            s1_p += sd*beta;
            sc_p += sd;
            const float4 q0 = *(const float4*)&s[oQc + i*8];
            const float4 q1 = *(const float4*)&s[oQc + i*8 + 4];
            const float vc = ci*v, vcc = ci*vc;
            t0[0]+=q0.x*v;   t0[1]+=q0.y*v;   t0[2]+=q0.z*v;   t0[3]+=q0.w*v;
            t0[4]+=q1.x*v;   t0[5]+=q1.y*v;   t0[6]+=q1.z*v;   t0[7]+=q1.w*v;
            t1[0]+=q0.x*vc;  t1[1]+=q0.y*vc;  t1[2]+=q0.z*vc;  t1[3]+=q0.w*vc;
            t1[4]+=q1.x*vc;  t1[5]+=q1.y*vc;  t1[6]+=q1.z*vc;  t1[7]+=q1.w*vc;
            t2[0]+=q0.x*vcc; t2[1]+=q0.y*vcc; t2[2]+=q0.z*vcc; t2[3]+=q0.w*vcc;
            t2[4]+=q1.x*vcc; t2[5]+=q1.y*vcc; t2[6]+=q1.z*vcc; t2[7]+=q1.w*vcc;
        }
    }
    // reduce T0 / T1 / T2 into T3[0..2]
    #pragma unroll
    for (int k = 0; k < 8; ++k) s[oTp + w*512 + k*64 + lane] = t0[k];
    __syncthreads();
    { float tt=0.0f;
      #pragma unroll
      for (int r=0;r<8;++r) tt += s[oTp + r*512 + w*64 + lane];
      s[oT3 + 0*8*TPAD + w*TPAD + lane] = tt; }
    __syncthreads();
    #pragma unroll
    for (int k = 0; k < 8; ++k) s[oTp + w*512 + k*64 + lane] = t1[k];
    __syncthreads();
    { float tt=0.0f;
      #pragma unroll
      for (int r=0;r<8;++r) tt += s[oTp + r*512 + w*64 + lane];
      s[oT3 + 1*8*TPAD + w*TPAD + lane] = tt; }
    __syncthreads();
    #pragma unroll
    for (int k = 0; k < 8; ++k) s[oTp + w*512 + k*64 + lane] = t2[k];
    __syncthreads();
    { float tt=0.0f;
      #pragma unroll
      for (int r=0;r<8;++r) tt += s[oTp + r*512 + w*64 + lane];
      s[oT3 + 2*8*TPAD + w*TPAD + lane] = tt; }
    __syncthreads();

    // M5: M00 = T0@Qc, M01 = T0@Qc1, M02 = T0@Qc2, M10 = T1@Qc, M20 = T2@Qc
    if (tid < 320) {
        const int a = tid >> 6;                 // wave-uniform
        const int src = (a < 3) ? 0 : (a - 2);
        float acc = 0.0f;
        for (int j = 0; j < 64; ++j) {
            const float tv = s[oT3 + src*8*TPAD + kk8*TPAD + j];
            float qv = s[oQcT + ll8*TPAD + j];
            if (a == 1)      qv *= s[oCd + j];
            else if (a == 2) { const float cj = s[oCd + j]; qv *= cj*cj; }
            acc += tv * qv;
        }
        s[oM5 + a*64 + lane] = acc;
    }
    __syncthreads();

    // wd_n = u * ((x^2+y^2) B00 + B20 + B02 - 2y B10 - 2x B01),  B_a = py^T M5[a] px
    float B5[5];
    #pragma unroll
    for (int a = 0; a < 5; ++a) {
        float acc = 0.0f;
        #pragma unroll
        for (int k = 0; k < 8; ++k) {
            const float4 m0 = *(const float4*)&s[oM5 + a*64 + k*8];
            const float4 m1 = *(const float4*)&s[oM5 + a*64 + k*8 + 4];
            const float t = m0.x*px[0]+m0.y*px[1]+m0.z*px[2]+m0.w*px[3]
                          + m1.x*px[4]+m1.y*px[5]+m1.z*px[6]+m1.w*px[7];
            acc += py[k]*t;
        }
        B5[a] = acc;
    }
    float wd_p = u * ((x*x + y*y)*B5[0] + B5[4] + B5[2] - 2.0f*y*B5[3] - 2.0f*x*B5[1]);

    // block reduction of the 4 scalars
    #pragma unroll
    for (int off = 32; off > 0; off >>= 1) {
        ot_p += __shfl_xor(ot_p, off, 64);
        s1_p += __shfl_xor(s1_p, off, 64);
        sc_p += __shfl_xor(sc_p, off, 64);
        wd_p += __shfl_xor(wd_p, off, 64);
    }
    if (lane == 0) {
        s[oRed + 0*8 + w] = ot_p;
        s[oRed + 1*8 + w] = s1_p;
        s[oRed + 2*8 + w] = sc_p;
        s[oRed + 3*8 + w] = wd_p;
    }
    __syncthreads();
    if (tid == 0) {
        float ot=0.0f, s1=0.0f, sc=0.0f, wd=0.0f;
        for (int r = 0; r < 8; ++r) {
            ot += s[oRed + 0*8 + r];
            s1 += s[oRed + 1*8 + r];
            sc += s[oRed + 2*8 + r];
            wd += s[oRed + 3*8 + r];
        }
        const float denom = sc*sc + 1e-8f;
        const float loss = (sc/denom)*s1 - sc*(s1/denom);   // analytically 0; rounding-level like ref
        atomicAdd(&out[0], loss);
        atomicAdd(&out[1], wd);
        atomicAdd(&out[2], ot);
    }
}

extern "C" void kernel_launch(void* const* d_in, const int* in_sizes, int n_in,
                              void* d_out, int out_size, void* d_ws, size_t ws_size,
                              hipStream_t stream)
{
    const float* nd  = (const float*)d_in[0];   // normed_density  (32*1*64*64)
    const float* ud  = (const float*)d_in[1];   // unnormed_density
    const float* pts = (const float*)d_in[2];   // points (32*512*2)
    float* out = (float*)d_out;

    (void)in_sizes; (void)n_in; (void)out_size; (void)d_ws; (void)ws_size;

    // 89 KB dynamic LDS (> 64 KB default cap); gfx950 allows up to 160 KB/WG.
    hipFuncSetAttribute((const void*)ot_sinkhorn_kernel,
                        hipFuncAttributeMaxDynamicSharedMemorySize,
                        (int)(LDS_FLOATS * sizeof(float)));

    // Harness does not re-zero d_out between timed replays.
    hipMemsetAsync(d_out, 0, 3 * sizeof(float), stream);

    ot_sinkhorn_kernel<<<dim3(32), dim3(512), LDS_FLOATS * sizeof(float), stream>>>(nd, ud, pts, out);
}

// Round 2
// 90.836 us; speedup vs baseline: 4.6706x; 4.6706x over previous
//
#include <hip/hip_runtime.h>
#include <math.h>

// 20 Sinkhorn iterations: Birkhoff contraction per full iteration is
// lambda^2 = 0.144 (K in [e^-0.8, 1], input-independent), so 20 iters is
// converged to ~1e-16 in Hilbert metric -- identical to the 100-iter
// reference within fp32 rounding.
constexpr int N_IT = 20;

// ---------------- LDS layout (float offsets) ----------------
constexpr int PS   = 516;   // padded stride for [8][512] arrays
constexpr int TPAD = 68;    // padded stride for [8][64] arrays
constexpr int oZt  = 0;                 // [8][PS]  z[k][n] = u_n * py[n,k]
constexpr int oPxt = oZt + 8*PS;        // [8][PS]  Px transposed (static)
constexpr int oQc  = oPxt + 8*PS;       // [64][8]
constexpr int oQcT = oQc + 512;         // [8][TPAD]
constexpr int oGp  = oQcT + 8*TPAD;     // [8][64]  per-wave G partials
constexpr int oG   = oGp + 512;         // [64]     G[t*8+k]
constexpr int oTp  = oG + 64;           // [8][8][64] T partials
constexpr int oT   = oTp + 4096;        // [8][TPAD]
constexpr int oMp  = oT + 8*TPAD;       // [8][64]  M partials
constexpr int oM   = oMp + 512;         // [64]     M[k*8+l]
constexpr int oM5  = oM + 64;           // [5][64]
constexpr int oCd  = oM5 + 320;         // [64]     grid coords
constexpr int oRed = oCd + 64;          // [4][8]
constexpr int oT3  = oZt;               // [3][8][TPAD] aliases Zt (dead after loop)
constexpr int LDS_FLOATS = oRed + 32;   // 15520 floats = 62080 B (< 64 KB)

__global__ __launch_bounds__(512)
void ot_sinkhorn_kernel(const float* __restrict__ nd,
                        const float* __restrict__ ud,
                        const float* __restrict__ pts,
                        float* __restrict__ out)
{
    extern __shared__ float s[];
    const int img  = blockIdx.x;
    const int tid  = threadIdx.x;
    const int lane = tid & 63;
    const int w    = tid >> 6;
    const int kk8  = lane >> 3, ll8 = lane & 7;

    // rs[k] = 1/sqrt(5^k * k!)  for exp(yc/5) = sum_k (y^k/s_k)(c^k/s_k)
    const float rs[8] = {1.0f, 0.44721359549995794f, 0.14142135623730950f,
                         0.036514837167011076f, 0.0081649658092772615f,
                         0.0016329931618554521f, 0.00029814239699997195f,
                         5.0395263067896967e-05f};

    // ---------------- per-thread point & basis ----------------
    const float2 p = ((const float2*)pts)[img*512 + tid];
    const float x = p.x * (1.0f/256.0f) - 1.0f;
    const float y = p.y * (1.0f/256.0f) - 1.0f;
    float px[8], py[8];
    {
        const float ex = expf(-x*x*0.1f);
        const float ey = expf(-y*y*0.1f);
        float xp = 1.0f, yp = 1.0f;
        #pragma unroll
        for (int k = 0; k < 8; ++k) {
            px[k] = ex * xp * rs[k];
            py[k] = ey * yp * rs[k];
            xp *= x; yp *= y;
        }
    }
    #pragma unroll
    for (int k = 0; k < 8; ++k) s[oPxt + k*PS + tid] = px[k];

    {   // Qc[i][k] = exp(-c^2/10) c^k / s_k , c = (8i+4)/256 - 1
        const int i = tid >> 3, k = tid & 7;
        const float c = (float)(i*8 + 4) * (1.0f/256.0f) - 1.0f;
        float cp = 1.0f;
        for (int kk = 0; kk < k; ++kk) cp *= c;
        const float q = expf(-c*c*0.1f) * cp * rs[k];
        s[oQc  + i*8    + k] = q;
        s[oQcT + k*TPAD + i] = q;
        if (k == 0) s[oCd + i] = c;
    }

    // b-values for this thread's (i = 8w+m, j = lane) cells: global, once.
    float bv[8];
    #pragma unroll
    for (int m = 0; m < 8; ++m)
        bv[m] = nd[(size_t)img*4096 + (8*w + m)*64 + lane];

    float u = 1.0f/512.0f;
    __syncthreads();

    // ---------------- iteration-invariant register hoists ----------------
    float qj[8];      // Qc[lane][k]        (C: R-compute)
    float qr[8][8];   // Qc[8w+m][k]        (C: uk + T-fold; final pass)
    float qd[8];      // QcT[ll8][8w+m]     (D)
    {
        const float4 a0 = *(const float4*)&s[oQc + lane*8];
        const float4 a1 = *(const float4*)&s[oQc + lane*8 + 4];
        qj[0]=a0.x; qj[1]=a0.y; qj[2]=a0.z; qj[3]=a0.w;
        qj[4]=a1.x; qj[5]=a1.y; qj[6]=a1.z; qj[7]=a1.w;
        #pragma unroll
        for (int m = 0; m < 8; ++m) {
            const float4 b0 = *(const float4*)&s[oQc + (8*w+m)*8];
            const float4 b1 = *(const float4*)&s[oQc + (8*w+m)*8 + 4];
            qr[m][0]=b0.x; qr[m][1]=b0.y; qr[m][2]=b0.z; qr[m][3]=b0.w;
            qr[m][4]=b1.x; qr[m][5]=b1.y; qr[m][6]=b1.z; qr[m][7]=b1.w;
        }
        const float4 d0 = *(const float4*)&s[oQcT + ll8*TPAD + 8*w];
        const float4 d1 = *(const float4*)&s[oQcT + ll8*TPAD + 8*w + 4];
        qd[0]=d0.x; qd[1]=d0.y; qd[2]=d0.z; qd[3]=d0.w;
        qd[4]=d1.x; qd[5]=d1.y; qd[6]=d1.z; qd[7]=d1.w;
    }

    // ---------------- Sinkhorn iterations (6 barriers each) ----------------
    for (int it = 0; it < N_IT; ++it) {
        // Z: publish z[k][n] = u_n py[n,k]  (own wave reads own columns only)
        #pragma unroll
        for (int k = 0; k < 8; ++k) s[oZt + k*PS + tid] = u * py[k];
        // A2: Gp[w][k,l] = sum_{n in wave} z[n,k] px[n,l]   (same-wave RAW, no barrier)
        {
            float acc = 0.0f;
            const int base = 64*w;
            #pragma unroll
            for (int c4 = 0; c4 < 16; ++c4) {
                const float4 z4 = *(const float4*)&s[oZt  + kk8*PS + base + 4*c4];
                const float4 p4 = *(const float4*)&s[oPxt + ll8*PS + base + 4*c4];
                acc += z4.x*p4.x + z4.y*p4.y + z4.z*p4.z + z4.w*p4.w;
            }
            s[oGp + w*64 + lane] = acc;
        }
        __syncthreads();                         // B1
        if (tid < 64) {                          // A3: reduce G
            float g = 0.0f;
            #pragma unroll
            for (int r = 0; r < 8; ++r) g += s[oGp + r*64 + tid];
            s[oG + tid] = g;
        }
        __syncthreads();                         // B2
        // C: R[t] = sum_k G[t,k] qj[k]; uk[i,j] = sum_t Qc[i,t] R[t]; fold T
        {
            float R[8];
            #pragma unroll
            for (int t = 0; t < 8; ++t) {
                const float4 g0 = *(const float4*)&s[oG + t*8];
                const float4 g1 = *(const float4*)&s[oG + t*8 + 4];
                R[t] = g0.x*qj[0]+g0.y*qj[1]+g0.z*qj[2]+g0.w*qj[3]
                     + g1.x*qj[4]+g1.y*qj[5]+g1.z*qj[6]+g1.w*qj[7];
            }
            float t0[8];
            #pragma unroll
            for (int k = 0; k < 8; ++k) t0[k] = 0.0f;
            #pragma unroll
            for (int m = 0; m < 8; ++m) {
                float uk = 0.0f;
                #pragma unroll
                for (int t = 0; t < 8; ++t) uk += qr[m][t] * R[t];
                const float v = bv[m] / (uk + 1e-16f);
                #pragma unroll
                for (int k = 0; k < 8; ++k) t0[k] += qr[m][k] * v;
            }
            #pragma unroll
            for (int k = 0; k < 8; ++k) s[oTp + w*512 + k*64 + lane] = t0[k];
        }
        __syncthreads();                         // B3
        {   // C2: T[k=w][j=lane] = sum_r Tp[r]
            float tt = 0.0f;
            #pragma unroll
            for (int r = 0; r < 8; ++r) tt += s[oTp + r*512 + w*64 + lane];
            s[oT + w*TPAD + lane] = tt;
        }
        __syncthreads();                         // B4
        {   // D: Mp[w][k,l] = sum_{j in 8w..8w+8} T[k,j] QcT[l,j]
            const float4 tA = *(const float4*)&s[oT + kk8*TPAD + 8*w];
            const float4 tB = *(const float4*)&s[oT + kk8*TPAD + 8*w + 4];
            const float md = tA.x*qd[0]+tA.y*qd[1]+tA.z*qd[2]+tA.w*qd[3]
                           + tB.x*qd[4]+tB.y*qd[5]+tB.z*qd[6]+tB.w*qd[7];
            s[oMp + w*64 + lane] = md;
        }
        __syncthreads();                         // B5
        if (tid < 64) {                          // D2: reduce M
            float mm = 0.0f;
            #pragma unroll
            for (int r = 0; r < 8; ++r) mm += s[oMp + r*64 + tid];
            s[oM + tid] = mm;
        }
        __syncthreads();                         // B6
        // E: Kv_n = py^T M px ; u = a/(Kv+eps)
        {
            float kv = 0.0f;
            #pragma unroll
            for (int k = 0; k < 8; ++k) {
                const float4 m0 = *(const float4*)&s[oM + k*8];
                const float4 m1 = *(const float4*)&s[oM + k*8 + 4];
                kv += py[k]*(m0.x*px[0]+m0.y*px[1]+m0.z*px[2]+m0.w*px[3]
                           + m1.x*px[4]+m1.y*px[5]+m1.z*px[6]+m1.w*px[7]);
            }
            u = (1.0f/512.0f) / (kv + 1e-16f);
        }
    }

    // ---------------- final pass: v from G (last iter), beta, wd ----------------
    float ot_p = 0.0f, s1_p = 0.0f, sc_p = 0.0f;
    float t0[8], t1[8], t2[8];
    {
        float R[8];
        #pragma unroll
        for (int t = 0; t < 8; ++t) {
            const float4 g0 = *(const float4*)&s[oG + t*8];
            const float4 g1 = *(const float4*)&s[oG + t*8 + 4];
            R[t] = g0.x*qj[0]+g0.y*qj[1]+g0.z*qj[2]+g0.w*qj[3]
                 + g1.x*qj[4]+g1.y*qj[5]+g1.z*qj[6]+g1.w*qj[7];
        }
        #pragma unroll
        for (int k = 0; k < 8; ++k) { t0[k]=0.0f; t1[k]=0.0f; t2[k]=0.0f; }
        #pragma unroll
        for (int m = 0; m < 8; ++m) {
            const int i = 8*w + m;
            const float ci = (float)(8*i + 4) * (1.0f/256.0f) - 1.0f;
            float uk = 0.0f;
            #pragma unroll
            for (int t = 0; t < 8; ++t) uk += qr[m][t] * R[t];
            const float v = bv[m] / (uk + 1e-16f);
            const float beta = 10.0f * logf(v + 1e-16f);
            const float sd = ud[(size_t)img*4096 + i*64 + lane];
            ot_p += bv[m]*beta;
            s1_p += sd*beta;
            sc_p += sd;
            const float vc = ci*v, vcc = ci*vc;
            #pragma unroll
            for (int k = 0; k < 8; ++k) {
                t0[k] += qr[m][k]*v;
                t1[k] += qr[m][k]*vc;
                t2[k] += qr[m][k]*vcc;
            }
        }
    }
    // reduce T0/T1/T2 into T3[0..2] (T3 aliases the now-dead Zt region)
    #pragma unroll
    for (int k = 0; k < 8; ++k) s[oTp + w*512 + k*64 + lane] = t0[k];
    __syncthreads();
    { float tt=0.0f;
      #pragma unroll
      for (int r=0;r<8;++r) tt += s[oTp + r*512 + w*64 + lane];
      __syncthreads();
      s[oT3 + 0*8*TPAD + w*TPAD + lane] = tt; }
    __syncthreads();
    #pragma unroll
    for (int k = 0; k < 8; ++k) s[oTp + w*512 + k*64 + lane] = t1[k];
    __syncthreads();
    { float tt=0.0f;
      #pragma unroll
      for (int r=0;r<8;++r) tt += s[oTp + r*512 + w*64 + lane];
      s[oT3 + 1*8*TPAD + w*TPAD + lane] = tt; }
    __syncthreads();
    #pragma unroll
    for (int k = 0; k < 8; ++k) s[oTp + w*512 + k*64 + lane] = t2[k];
    __syncthreads();
    { float tt=0.0f;
      #pragma unroll
      for (int r=0;r<8;++r) tt += s[oTp + r*512 + w*64 + lane];
      s[oT3 + 2*8*TPAD + w*TPAD + lane] = tt; }
    __syncthreads();

    // M5: M00=T0@Qc, M01=T0@Qc1, M02=T0@Qc2, M10=T1@Qc, M20=T2@Qc
    if (tid < 320) {
        const int a = tid >> 6;                 // wave-uniform
        const int src = (a < 3) ? 0 : (a - 2);
        float acc = 0.0f;
        for (int j = 0; j < 64; ++j) {
            const float tv = s[oT3 + src*8*TPAD + kk8*TPAD + j];
            float qv = s[oQcT + ll8*TPAD + j];
            if (a == 1)      qv *= s[oCd + j];
            else if (a == 2) { const float cj = s[oCd + j]; qv *= cj*cj; }
            acc += tv * qv;
        }
        s[oM5 + a*64 + lane] = acc;
    }
    __syncthreads();

    // wd_n = u * ((x^2+y^2) B00 + B20 + B02 - 2y B10 - 2x B01)
    float B5[5];
    #pragma unroll
    for (int a = 0; a < 5; ++a) {
        float acc = 0.0f;
        #pragma unroll
        for (int k = 0; k < 8; ++k) {
            const float4 m0 = *(const float4*)&s[oM5 + a*64 + k*8];
            const float4 m1 = *(const float4*)&s[oM5 + a*64 + k*8 + 4];
            acc += py[k]*(m0.x*px[0]+m0.y*px[1]+m0.z*px[2]+m0.w*px[3]
                        + m1.x*px[4]+m1.y*px[5]+m1.z*px[6]+m1.w*px[7]);
        }
        B5[a] = acc;
    }
    float wd_p = u * ((x*x + y*y)*B5[0] + B5[4] + B5[2] - 2.0f*y*B5[3] - 2.0f*x*B5[1]);

    // block reduction of the 4 scalars
    #pragma unroll
    for (int off = 32; off > 0; off >>= 1) {
        ot_p += __shfl_xor(ot_p, off, 64);
        s1_p += __shfl_xor(s1_p, off, 64);
        sc_p += __shfl_xor(sc_p, off, 64);
        wd_p += __shfl_xor(wd_p, off, 64);
    }
    if (lane == 0) {
        s[oRed + 0*8 + w] = ot_p;
        s[oRed + 1*8 + w] = s1_p;
        s[oRed + 2*8 + w] = sc_p;
        s[oRed + 3*8 + w] = wd_p;
    }
    __syncthreads();
    if (tid == 0) {
        float ot=0.0f, s1=0.0f, sc=0.0f, wd=0.0f;
        for (int r = 0; r < 8; ++r) {
            ot += s[oRed + 0*8 + r];
            s1 += s[oRed + 1*8 + r];
            sc += s[oRed + 2*8 + r];
            wd += s[oRed + 3*8 + r];
        }
        const float denom = sc*sc + 1e-8f;
        const float loss = (sc/denom)*s1 - sc*(s1/denom);   // analytically 0
        atomicAdd(&out[0], loss);
        atomicAdd(&out[1], wd);
        atomicAdd(&out[2], ot);
    }
}

extern "C" void kernel_launch(void* const* d_in, const int* in_sizes, int n_in,
                              void* d_out, int out_size, void* d_ws, size_t ws_size,
                              hipStream_t stream)
{
    const float* nd  = (const float*)d_in[0];   // normed_density  (32*1*64*64)
    const float* ud  = (const float*)d_in[1];   // unnormed_density
    const float* pts = (const float*)d_in[2];   // points (32*512*2)
    float* out = (float*)d_out;

    (void)in_sizes; (void)n_in; (void)out_size; (void)d_ws; (void)ws_size;

    hipFuncSetAttribute((const void*)ot_sinkhorn_kernel,
                        hipFuncAttributeMaxDynamicSharedMemorySize,
                        (int)(LDS_FLOATS * sizeof(float)));

    // Harness does not re-zero d_out between timed replays.
    hipMemsetAsync(d_out, 0, 3 * sizeof(float), stream);

    ot_sinkhorn_kernel<<<dim3(32), dim3(512), LDS_FLOATS * sizeof(float), stream>>>(nd, ud, pts, out);
}